// Round 1
// baseline (396.165 us; speedup 1.0000x reference)
//
#include <hip/hip_runtime.h>
#include <hip/hip_bf16.h>

// Problem: B=128, N=65536, H-ish h=30.
// Inputs (flat element counts):
//  0 proposal_feat   [B,64]    f32   (unused)
//  1 target_candidate[B,N,2]   f32   (unused)
//  2 candidate       [B*N,2]   f32
//  3 RCNN_cls_result [B,N,2]   f32   (passthrough to out)
//  4 offset          [B,N,2]   f32
//  5 yaw_pred        [B,1]     f32   (unused)
//  6 y               [B*h*2]   f32
//  7 y_yaw           [B*h]     f32   (unused)
//  8 horizon         [B]       i32   (unused)
// Output: RCNN_cls_result flat (B*N*2 floats) ++ loss (1 float).
//
// Key algebraic simplification: the argsort gather is a full per-row
// permutation, and d2 is summed over ALL columns afterwards -> the sort is
// irrelevant to the loss. loss = sum_b sum_i ||gt[b] - (cand[b,i]+off[b,i])||^2.

__global__ __launch_bounds__(128) void gt_and_zero_kernel(
    const float* __restrict__ y, float* __restrict__ gt /* [2B] */,
    float* __restrict__ loss_slot, int h)
{
    int b = threadIdx.x;            // one block of B threads
    const float* yb = y + (size_t)b * h * 2;
    float gx = 0.f, gy = 0.f;
    for (int t = 0; t < h; ++t) { gx += yb[2*t]; gy += yb[2*t + 1]; }
    gt[2*b]     = gx;
    gt[2*b + 1] = gy;
    if (b == 0) *loss_slot = 0.f;
}

__global__ __launch_bounds__(256) void copy_and_loss_kernel(
    const float4* __restrict__ cand,
    const float4* __restrict__ off,
    const float4* __restrict__ rcnn,
    float4* __restrict__ out,
    const float* __restrict__ gt,
    float* __restrict__ loss_slot,
    int n4, int log_row4)           // n4 = B*N/2 float4s; row4 = N/2 per row
{
    int idx = blockIdx.x * blockDim.x + threadIdx.x;
    float acc = 0.f;
    if (idx < n4) {
        float4 c = cand[idx];
        float4 o = off[idx];
        float4 r = rcnn[idx];
        out[idx] = r;               // passthrough of RCNN_cls_result
        int b = idx >> log_row4;
        float gx = gt[2*b], gy = gt[2*b + 1];   // L1/L2-resident broadcast
        float dx0 = gx - (c.x + o.x);
        float dy0 = gy - (c.y + o.y);
        float dx1 = gx - (c.z + o.z);
        float dy1 = gy - (c.w + o.w);
        acc = dx0*dx0 + dy0*dy0 + dx1*dx1 + dy1*dy1;
    }
    // wave-64 butterfly reduce
    #pragma unroll
    for (int s = 32; s > 0; s >>= 1) acc += __shfl_down(acc, s, 64);
    __shared__ float lds[4];
    int lane = threadIdx.x & 63, wid = threadIdx.x >> 6;
    if (lane == 0) lds[wid] = acc;
    __syncthreads();
    if (threadIdx.x == 0) {
        float s = lds[0] + lds[1] + lds[2] + lds[3];
        atomicAdd(loss_slot, s);    // ~16K atomics to one address: negligible
    }
}

extern "C" void kernel_launch(void* const* d_in, const int* in_sizes, int n_in,
                              void* d_out, int out_size, void* d_ws, size_t ws_size,
                              hipStream_t stream) {
    const float* candidate = (const float*)d_in[2];
    const float* rcnn      = (const float*)d_in[3];
    const float* offset    = (const float*)d_in[4];
    const float* y         = (const float*)d_in[6];

    const int B = in_sizes[8];                 // horizon is [B]
    const int N = in_sizes[3] / (B * 2);       // RCNN is [B,N,2]
    const int h = in_sizes[6] / (B * 2);       // y is [B*h*2]

    float* out_f     = (float*)d_out;
    float* loss_slot = out_f + (size_t)B * N * 2;   // last element of d_out
    float* gt        = (float*)d_ws;                // 2*B floats scratch

    gt_and_zero_kernel<<<1, B, 0, stream>>>(y, gt, loss_slot, h);

    const int n4 = (B * N * 2) / 4;            // float4 count = B*N/2
    const int row4 = N / 2;                    // float4s per sample row
    int log_row4 = 0;
    while ((1 << log_row4) < row4) ++log_row4; // N is a power of two here

    const int block = 256;
    const int grid = (n4 + block - 1) / block; // 16384 blocks
    copy_and_loss_kernel<<<grid, block, 0, stream>>>(
        (const float4*)candidate, (const float4*)offset, (const float4*)rcnn,
        (float4*)d_out, gt, loss_slot, n4, log_row4);
}

// Round 2
// 262.199 us; speedup vs baseline: 1.5109x; 1.5109x over previous
//
#include <hip/hip_runtime.h>
#include <hip/hip_bf16.h>

// Problem: B=128, N=65536, h=30.
// loss = sum_b sum_i ||gt[b] - (cand[b,i]+off[b,i])||^2  (argsort is a full
// permutation summed over afterwards -> irrelevant). RCNN passthrough.
// Output: RCNN_cls_result flat (B*N*2 floats) ++ loss (1 float).
//
// R1 lesson: 16384 same-address atomicAdds serialized at ~13ns each = the
// entire 216us kernel time. This version: block partials to d_ws + tiny
// final-reduce kernel. Zero atomics.

__global__ __launch_bounds__(64) void gt_kernel(
    const float* __restrict__ y, float* __restrict__ gt /* [2B] */, int h)
{
    int b = blockIdx.x;
    int t = threadIdx.x;
    float gx = 0.f, gy = 0.f;
    for (int i = t; i < h; i += 64) {
        float2 v = ((const float2*)y)[(size_t)b * h + i];
        gx += v.x; gy += v.y;
    }
    #pragma unroll
    for (int s = 32; s > 0; s >>= 1) {
        gx += __shfl_down(gx, s, 64);
        gy += __shfl_down(gy, s, 64);
    }
    if (t == 0) { gt[2*b] = gx; gt[2*b + 1] = gy; }
}

// Each block owns a contiguous chunk of ITERS*256 float4s. With N/2 = 32768
// float4s per batch row and chunks of 2048, every chunk sits inside one row.
__global__ __launch_bounds__(256) void copy_and_loss_kernel(
    const float4* __restrict__ cand,
    const float4* __restrict__ off,
    const float4* __restrict__ rcnn,
    float4* __restrict__ out,
    const float* __restrict__ gt,
    float* __restrict__ partials,   // [gridDim.x]
    int n4, int log_row4, int iters)
{
    const size_t base = (size_t)blockIdx.x * (size_t)blockDim.x * iters;
    float acc = 0.f;
    for (int k = 0; k < iters; ++k) {
        size_t idx = base + (size_t)k * blockDim.x + threadIdx.x;
        if (idx < (size_t)n4) {
            float4 c = cand[idx];
            float4 o = off[idx];
            float4 r = rcnn[idx];
            out[idx] = r;                       // RCNN passthrough
            int b = (int)(idx >> log_row4);
            float gx = gt[2*b], gy = gt[2*b + 1];  // broadcast, L1-resident
            float dx0 = gx - (c.x + o.x);
            float dy0 = gy - (c.y + o.y);
            float dx1 = gx - (c.z + o.z);
            float dy1 = gy - (c.w + o.w);
            acc += dx0*dx0 + dy0*dy0 + dx1*dx1 + dy1*dy1;
        }
    }
    // wave-64 reduce, then 4 waves -> LDS -> thread 0
    #pragma unroll
    for (int s = 32; s > 0; s >>= 1) acc += __shfl_down(acc, s, 64);
    __shared__ float lds[4];
    int lane = threadIdx.x & 63, wid = threadIdx.x >> 6;
    if (lane == 0) lds[wid] = acc;
    __syncthreads();
    if (threadIdx.x == 0)
        partials[blockIdx.x] = lds[0] + lds[1] + lds[2] + lds[3];
}

__global__ __launch_bounds__(256) void final_reduce_kernel(
    const float* __restrict__ partials, float* __restrict__ loss_slot, int n)
{
    float acc = 0.f;
    for (int i = threadIdx.x; i < n; i += 256) acc += partials[i];
    #pragma unroll
    for (int s = 32; s > 0; s >>= 1) acc += __shfl_down(acc, s, 64);
    __shared__ float lds[4];
    int lane = threadIdx.x & 63, wid = threadIdx.x >> 6;
    if (lane == 0) lds[wid] = acc;
    __syncthreads();
    if (threadIdx.x == 0)
        *loss_slot = lds[0] + lds[1] + lds[2] + lds[3];
}

extern "C" void kernel_launch(void* const* d_in, const int* in_sizes, int n_in,
                              void* d_out, int out_size, void* d_ws, size_t ws_size,
                              hipStream_t stream) {
    const float* candidate = (const float*)d_in[2];
    const float* rcnn      = (const float*)d_in[3];
    const float* offset    = (const float*)d_in[4];
    const float* y         = (const float*)d_in[6];

    const int B = in_sizes[8];                 // horizon is [B]
    const int N = in_sizes[3] / (B * 2);       // RCNN is [B,N,2]
    const int h = in_sizes[6] / (B * 2);       // y is [B*h,2]

    float* out_f     = (float*)d_out;
    float* loss_slot = out_f + (size_t)B * N * 2;   // last element of d_out

    float* gt       = (float*)d_ws;                 // 2*B floats
    float* partials = gt + 2 * B;                   // gridDim floats

    gt_kernel<<<B, 64, 0, stream>>>(y, gt, h);

    const int n4 = (B * N * 2) / 4;            // 4,194,304 float4s
    const int row4 = N / 2;
    int log_row4 = 0;
    while ((1 << log_row4) < row4) ++log_row4;

    const int block = 256;
    const int grid  = 2048;                    // 8 blocks/CU
    const int iters = (n4 + grid * block - 1) / (grid * block);  // = 8
    copy_and_loss_kernel<<<grid, block, 0, stream>>>(
        (const float4*)candidate, (const float4*)offset, (const float4*)rcnn,
        (float4*)d_out, gt, partials, n4, log_row4, iters);

    final_reduce_kernel<<<1, 256, 0, stream>>>(partials, loss_slot, grid);
}

// Round 4
// 262.176 us; speedup vs baseline: 1.5111x; 1.0001x over previous
//
#include <hip/hip_runtime.h>
#include <hip/hip_bf16.h>

// Problem: B=128, N=65536, h=30.
// loss = sum_b sum_i ||gt[b] - (cand[b,i]+off[b,i])||^2  (argsort is a full
// permutation summed over afterwards -> irrelevant). RCNN passthrough.
// Output: RCNN_cls_result flat (B*N*2 floats) ++ loss (1 float).
//
// R1 lesson: same-address atomics serialize (~13ns each) -> block partials.
// R2 lesson: per-iter loop w/ bounds check = 3 loads in flight per wave ->
//   latency-bound at 1.9 TB/s. Fix: issue all 12 float4 loads up front.
// R3 lesson: __builtin_nontemporal_store needs a clang ext_vector type, not
//   HIP's float4 class.

typedef float v4f __attribute__((ext_vector_type(4)));

__global__ __launch_bounds__(256) void copy_and_loss_kernel(
    const v4f* __restrict__ cand,
    const v4f* __restrict__ off,
    const v4f* __restrict__ rcnn,
    v4f* __restrict__ out,
    const float* __restrict__ y,     // [B*h*2]
    float* __restrict__ partials,    // [gridDim.x]
    int n4, int log_row4, int h)
{
    constexpr int U = 4;
    const size_t base = (size_t)blockIdx.x * (256 * U);
    const int b = (int)(base >> log_row4);   // uniform per block (chunk < row)

    // gt[b] computed redundantly per block; b is wave-uniform so these are
    // scalar-path loads of a 240B row (L2/L3-resident after first toucher).
    float gx = 0.f, gy = 0.f;
    {
        const float2* yb = (const float2*)y + (size_t)b * h;
        for (int i = 0; i < h; ++i) { float2 v = yb[i]; gx += v.x; gy += v.y; }
    }

    float acc = 0.f;
    if (base + 256 * U <= (size_t)n4) {      // uniform fast path (exact grid)
        v4f c[U], o[U], r[U];
        #pragma unroll
        for (int u = 0; u < U; ++u) c[u] = cand[base + u * 256 + threadIdx.x];
        #pragma unroll
        for (int u = 0; u < U; ++u) o[u] = off[base + u * 256 + threadIdx.x];
        #pragma unroll
        for (int u = 0; u < U; ++u) r[u] = rcnn[base + u * 256 + threadIdx.x];
        #pragma unroll
        for (int u = 0; u < U; ++u) {
            __builtin_nontemporal_store(r[u], &out[base + u * 256 + threadIdx.x]);
            float dx0 = gx - (c[u].x + o[u].x);
            float dy0 = gy - (c[u].y + o[u].y);
            float dx1 = gx - (c[u].z + o[u].z);
            float dy1 = gy - (c[u].w + o[u].w);
            acc += dx0*dx0 + dy0*dy0 + dx1*dx1 + dy1*dy1;
        }
    } else {                                  // tail (not taken for B=128,N=64K)
        #pragma unroll
        for (int u = 0; u < U; ++u) {
            size_t idx = base + u * 256 + threadIdx.x;
            if (idx < (size_t)n4) {
                v4f c = cand[idx], o = off[idx], r = rcnn[idx];
                __builtin_nontemporal_store(r, &out[idx]);
                float dx0 = gx - (c.x + o.x);
                float dy0 = gy - (c.y + o.y);
                float dx1 = gx - (c.z + o.z);
                float dy1 = gy - (c.w + o.w);
                acc += dx0*dx0 + dy0*dy0 + dx1*dx1 + dy1*dy1;
            }
        }
    }

    // wave-64 reduce, 4 waves -> LDS -> thread 0
    #pragma unroll
    for (int s = 32; s > 0; s >>= 1) acc += __shfl_down(acc, s, 64);
    __shared__ float lds[4];
    int lane = threadIdx.x & 63, wid = threadIdx.x >> 6;
    if (lane == 0) lds[wid] = acc;
    __syncthreads();
    if (threadIdx.x == 0)
        partials[blockIdx.x] = lds[0] + lds[1] + lds[2] + lds[3];
}

__global__ __launch_bounds__(256) void final_reduce_kernel(
    const float* __restrict__ partials, float* __restrict__ loss_slot, int n)
{
    float acc = 0.f;
    for (int i = threadIdx.x; i < n; i += 256) acc += partials[i];
    #pragma unroll
    for (int s = 32; s > 0; s >>= 1) acc += __shfl_down(acc, s, 64);
    __shared__ float lds[4];
    int lane = threadIdx.x & 63, wid = threadIdx.x >> 6;
    if (lane == 0) lds[wid] = acc;
    __syncthreads();
    if (threadIdx.x == 0)
        *loss_slot = lds[0] + lds[1] + lds[2] + lds[3];
}

extern "C" void kernel_launch(void* const* d_in, const int* in_sizes, int n_in,
                              void* d_out, int out_size, void* d_ws, size_t ws_size,
                              hipStream_t stream) {
    const float* candidate = (const float*)d_in[2];
    const float* rcnn      = (const float*)d_in[3];
    const float* offset    = (const float*)d_in[4];
    const float* y         = (const float*)d_in[6];

    const int B = in_sizes[8];                 // horizon is [B]
    const int N = in_sizes[3] / (B * 2);       // RCNN is [B,N,2]
    const int h = in_sizes[6] / (B * 2);       // y is [B*h,2]

    float* out_f     = (float*)d_out;
    float* loss_slot = out_f + (size_t)B * N * 2;   // last element of d_out
    float* partials  = (float*)d_ws;

    const int n4 = (B * N * 2) / 4;            // 4,194,304 float4s
    const int row4 = N / 2;                    // 32768 float4s per sample row
    int log_row4 = 0;
    while ((1 << log_row4) < row4) ++log_row4;

    const int block = 256;
    constexpr int U = 4;
    const int grid = (n4 + block * U - 1) / (block * U);   // 4096, exact
    copy_and_loss_kernel<<<grid, block, 0, stream>>>(
        (const v4f*)candidate, (const v4f*)offset, (const v4f*)rcnn,
        (v4f*)d_out, y, partials, n4, log_row4, h);

    final_reduce_kernel<<<1, 256, 0, stream>>>(partials, loss_slot, grid);
}